// Round 2
// baseline (936.297 us; speedup 1.0000x reference)
//
#include <hip/hip_runtime.h>

#define HALF 128
#define NMAT 16384   // 128*128
#define NTOK 131072  // 32*4096

// ---------------------------------------------------------------------------
// K1: fused Cayley -> QT.  Since M = I-A/2 and N = I+A/2 commute:
//     Q^T = N^{-1} M = N^{-1}(2I - N) = 2 N^{-1} - I.
// So: invert N once (Gauss-Jordan, no pivoting -- sym part of N is I, so all
// Schur pivots > 0), emit QT = 2*Ninv - I directly. No second matmul.
//
// Parallelization: register-resident columns. Thread t owns rows
// [h*64, h*64+64) of column c (c = t&127, h = t>>7) in 64 VGPRs.
// Per step k: owners publish col k (pre-update) + row k (pre-scale) to
// double-buffered LDS (double-buffer removes the WAR barrier -> 1 barrier
// per step), then all threads update their registers: broadcast LDS reads,
// 64 FMAs, no LDS RMW, no aliasing serialization.
// ---------------------------------------------------------------------------
__global__ __launch_bounds__(256) void cayley_qt(const float* __restrict__ prim,
                                                 float* __restrict__ QT) {
    __shared__ float Xs[128 * 129];      // +1 pad: both triangle reads conflict-free
    __shared__ float colk[2][128];
    __shared__ float rowk[2][128];

    const int b = blockIdx.x;
    const float* __restrict__ X = prim + b * NMAT;
    const int t  = threadIdx.x;
    const int c  = t & 127;
    const int h  = t >> 7;
    const int r0 = h << 6;

    // Stage X into padded LDS (coalesced float4 global reads, scalar LDS writes).
    for (int idx4 = t; idx4 < 4096; idx4 += 256) {
        int gi = idx4 << 2;
        float4 v = *(const float4*)(X + gi);
        int r = gi >> 7, cc = gi & 127;
        float* p = &Xs[r * 129 + cc];
        p[0] = v.x; p[1] = v.y; p[2] = v.z; p[3] = v.w;
    }
    __syncthreads();

    // reg[i] = N[r0+i][c] = (r==c) + 0.5*A[r][c];  A = tril(X) - tril(X)^T.
    float reg[64];
    #pragma unroll
    for (int i = 0; i < 64; ++i) {
        int r  = r0 + i;
        int mx = r > c ? r : c;
        int mn = r ^ c ^ mx;
        float x = Xs[mx * 129 + mn];          // single LDS read, ~conflict-free
        reg[i] = (r == c) ? 1.0f : (r > c ? 0.5f * x : -0.5f * x);
    }

    // In-place Gauss-Jordan on N (no pivoting).
    for (int k = 0; k < 128; ++k) {
        const int p  = k & 1;
        const int kh = k >> 6;
        const int kl = k & 63;
        if (c == k) {
            #pragma unroll
            for (int i = 0; i < 64; i += 4)
                *(float4*)&colk[p][r0 + i] =
                    make_float4(reg[i], reg[i+1], reg[i+2], reg[i+3]);
        }
        if (kh == h) rowk[p][c] = reg[kl];
        __syncthreads();

        float d = 1.0f / colk[p][k];
        if (c == k) {
            float nd = -d;
            #pragma unroll
            for (int i = 0; i < 64; ++i) reg[i] *= nd;
            if (kh == h) reg[kl] = d;
        } else {
            float s = rowk[p][c] * d;          // new a[k][c]
            #pragma unroll
            for (int i = 0; i < 64; i += 4) {
                float4 ck = *(const float4*)&colk[p][r0 + i];  // broadcast read
                reg[i+0] -= ck.x * s;
                reg[i+1] -= ck.y * s;
                reg[i+2] -= ck.z * s;
                reg[i+3] -= ck.w * s;
            }
            if (kh == h) reg[kl] = s;          // row-k entry: FMA drove it to 0
        }
        // no second barrier: next step publishes into buffer p^1 (no WAR)
    }

    // QT[r][c] = 2*Ninv[r][c] - (r==c); lane=c -> coalesced stores.
    float* __restrict__ out = QT + b * NMAT;
    #pragma unroll
    for (int i = 0; i < 64; ++i) {
        int r = r0 + i;
        out[r * HALF + c] = 2.0f * reg[i] - (r == c ? 1.0f : 0.0f);
    }
}

// ---------------------------------------------------------------------------
// K2: path table P[v][j] = f(v) for all v in [0,4096).
// v = identity; for d: b = bit d of v if (v>>(d+1))>0 else skip; v = v @ Q_b^T
// out[j] = sum_k v[k] * QT[b][k][j].  8 rows/block, k-split over 2 thread halves.
// ---------------------------------------------------------------------------
__global__ __launch_bounds__(256) void path_table(const float* __restrict__ QT,
                                                  const float* __restrict__ ident,
                                                  float* __restrict__ P) {
    __shared__ float vs[8][HALF];
    __shared__ float part[8][HALF];
    const int tid = threadIdx.x;
    const int j   = tid & 127;
    const int kh  = tid >> 7;          // k-half: 0 or 1
    const int k0  = kh << 6;
    const int vbase = blockIdx.x << 3;

    if (tid < 128) {
        float idv = ident[j];
        #pragma unroll
        for (int r = 0; r < 8; ++r) vs[r][j] = idv;
    }
    __syncthreads();

    const float* __restrict__ Q0 = QT;
    const float* __restrict__ Q1 = QT + NMAT;

    for (int d = 0; d < 13; ++d) {
        if (((vbase + 7) >> (d + 1)) == 0) break;   // block-uniform early exit
        int bb[8]; bool need0 = false, need1 = false;
        #pragma unroll
        for (int r = 0; r < 8; ++r) {
            int u = vbase + r;
            bb[r] = ((u >> (d + 1)) > 0) ? ((u >> d) & 1) : 2;
            need0 |= (bb[r] == 0);
            need1 |= (bb[r] == 1);
        }
        float acc[8] = {0.f,0.f,0.f,0.f,0.f,0.f,0.f,0.f};
        for (int k = k0; k < k0 + 64; k += 4) {
            float q00=0.f,q01=0.f,q02=0.f,q03=0.f,q10=0.f,q11=0.f,q12=0.f,q13=0.f;
            if (need0) {
                q00 = Q0[(k+0)*HALF + j]; q01 = Q0[(k+1)*HALF + j];
                q02 = Q0[(k+2)*HALF + j]; q03 = Q0[(k+3)*HALF + j];
            }
            if (need1) {
                q10 = Q1[(k+0)*HALF + j]; q11 = Q1[(k+1)*HALF + j];
                q12 = Q1[(k+2)*HALF + j]; q13 = Q1[(k+3)*HALF + j];
            }
            #pragma unroll
            for (int r = 0; r < 8; ++r) {
                if (bb[r] != 2) {
                    float4 vv = *(const float4*)&vs[r][k];   // broadcast read
                    if (bb[r] == 0) acc[r] += vv.x*q00 + vv.y*q01 + vv.z*q02 + vv.w*q03;
                    else            acc[r] += vv.x*q10 + vv.y*q11 + vv.z*q12 + vv.w*q13;
                }
            }
        }
        __syncthreads();                  // all vs reads complete
        if (kh == 1) {
            #pragma unroll
            for (int r = 0; r < 8; ++r) part[r][j] = acc[r];
        }
        __syncthreads();
        if (kh == 0) {
            #pragma unroll
            for (int r = 0; r < 8; ++r)
                if (bb[r] != 2) vs[r][j] = acc[r] + part[r][j];
        }
        __syncthreads();                  // writes visible before next step's reads
    }

    if (tid < 128) {
        #pragma unroll
        for (int r = 0; r < 8; ++r) P[(vbase + r) * HALF + j] = vs[r][j];
    }
}

// ---------------------------------------------------------------------------
// K3: emit output [B,S,256]: content (types/embeds/db->P[tv]) ++ pos (P[np]).
// unique/searchsorted bypassed: db token_values are always present positions.
// ---------------------------------------------------------------------------
__global__ __launch_bounds__(256) void emit_out(const int* __restrict__ tt,
                                                const int* __restrict__ tv,
                                                const int* __restrict__ np,
                                                const float* __restrict__ P,
                                                const float* __restrict__ emb,
                                                float* __restrict__ out) {
    const int base = blockIdx.x * 16;
    const int j = threadIdx.x;
    for (int s = 0; s < 16; ++s) {
        int i = base + s;
        int t = tt[i], v = tv[i], p = np[i];   // uniform -> scalar loads
        float val;
        if (j < 128) {
            if (t == 0)      val = emb[j];
            else if (t == 1) val = emb[(v + 1) * HALF + j];
            else if (t == 2) val = emb[(v + 5) * HALF + j];
            else if (t == 4) {
                int vc = v < 0 ? 0 : (v > 4095 ? 4095 : v);
                val = P[vc * HALF + j];
            } else           val = (v == -1) ? emb[10 * HALF + j] : 0.0f;
        } else {
            val = P[p * HALF + (j - 128)];
        }
        out[i * 256 + j] = val;
    }
}

extern "C" void kernel_launch(void* const* d_in, const int* in_sizes, int n_in,
                              void* d_out, int out_size, void* d_ws, size_t ws_size,
                              hipStream_t stream) {
    const int*   token_types = (const int*)  d_in[0];
    const int*   token_vals  = (const int*)  d_in[1];
    const int*   node_pos    = (const int*)  d_in[2];
    const float* prim        = (const float*)d_in[3];
    const float* ident       = (const float*)d_in[4];
    const float* emb         = (const float*)d_in[5];
    float* out = (float*)d_out;

    // workspace layout: QT[2][128][128] | (gap) | P[4096][128]
    float* QT = (float*)d_ws;
    float* P  = (float*)((char*)d_ws + 262144);

    cayley_qt  <<<2,   256, 0, stream>>>(prim, QT);
    path_table <<<512, 256, 0, stream>>>(QT, ident, P);
    emit_out   <<<NTOK / 16, 256, 0, stream>>>(token_types, token_vals, node_pos,
                                               P, emb, out);
}

// Round 3
// 611.617 us; speedup vs baseline: 1.5309x; 1.5309x over previous
//
#include <hip/hip_runtime.h>

#define HALF 128
#define NMAT 16384   // 128*128
#define NTOK 131072  // 32*4096

// ---------------------------------------------------------------------------
// K1: fused Cayley -> QT.  Q^T = N^{-1}(2I - N) = 2 N^{-1} - I,  N = I + A/2.
// Register-resident Gauss-Jordan, NO dynamic register indexing (round-2
// lesson: reg[runtime] forces the array to scratch -> 128KB spill traffic).
// Row-k fixup and row-(k+1) publish are wave-uniform selects over the
// constant-index unrolled loop.
// ---------------------------------------------------------------------------
__global__ __launch_bounds__(256) void cayley_qt(const float* __restrict__ prim,
                                                 float* __restrict__ QT) {
    __shared__ float Xs[128 * 129];      // +1 pad: conflict-free triangle reads
    __shared__ float colk[2][128];
    __shared__ float rowk[2][128];

    const int b = blockIdx.x;
    const float* __restrict__ X = prim + b * NMAT;
    const int t  = threadIdx.x;
    const int c  = t & 127;              // owned column
    const int h  = t >> 7;               // row half (wave-uniform)
    const int r0 = h << 6;

    for (int idx4 = t; idx4 < 4096; idx4 += 256) {
        int gi = idx4 << 2;
        float4 v = *(const float4*)(X + gi);
        int r = gi >> 7, cc = gi & 127;
        float* p = &Xs[r * 129 + cc];
        p[0] = v.x; p[1] = v.y; p[2] = v.z; p[3] = v.w;
    }
    __syncthreads();

    // reg[i] = N[r0+i][c];  A = tril(X) - tril(X)^T
    float reg[64];
    #pragma unroll
    for (int i = 0; i < 64; ++i) {
        int r  = r0 + i;
        int mx = r > c ? r : c;
        int mn = r ^ c ^ mx;
        float x = Xs[mx * 129 + mn];
        reg[i] = (r == c) ? 1.0f : (r > c ? 0.5f * x : -0.5f * x);
    }

    if (h == 0) rowk[0][c] = reg[0];     // bootstrap row 0 (constant index)

    for (int k = 0; k < 128; ++k) {
        const int p = k & 1;
        const int q = p ^ 1;
        if (c == k) {                    // publish pre-step column k
            #pragma unroll
            for (int i = 0; i < 64; i += 4)
                *(float4*)&colk[p][r0 + i] =
                    make_float4(reg[i], reg[i+1], reg[i+2], reg[i+3]);
        }
        __syncthreads();

        const float d = 1.0f / colk[p][k];
        float nextrow = 0.0f;            // new a[k+1][c], published for step k+1
        if (c == k) {
            const float nd = -d;
            #pragma unroll
            for (int i = 0; i < 64; ++i) {
                float nv = reg[i] * nd;
                nv = (r0 + i == k) ? d : nv;          // wave-uniform select
                nextrow = (r0 + i == k + 1) ? nv : nextrow;
                reg[i] = nv;
            }
        } else {
            const float s = rowk[p][c] * d;           // new a[k][c]
            #pragma unroll
            for (int i = 0; i < 64; i += 4) {
                float4 ck = *(const float4*)&colk[p][r0 + i];  // broadcast
                float n0 = fmaf(-ck.x, s, reg[i+0]);
                float n1 = fmaf(-ck.y, s, reg[i+1]);
                float n2 = fmaf(-ck.z, s, reg[i+2]);
                float n3 = fmaf(-ck.w, s, reg[i+3]);
                n0 = (r0+i+0 == k) ? s : n0;
                n1 = (r0+i+1 == k) ? s : n1;
                n2 = (r0+i+2 == k) ? s : n2;
                n3 = (r0+i+3 == k) ? s : n3;
                nextrow = (r0+i+0 == k+1) ? n0 : nextrow;
                nextrow = (r0+i+1 == k+1) ? n1 : nextrow;
                nextrow = (r0+i+2 == k+1) ? n2 : nextrow;
                nextrow = (r0+i+3 == k+1) ? n3 : nextrow;
                reg[i+0]=n0; reg[i+1]=n1; reg[i+2]=n2; reg[i+3]=n3;
            }
        }
        if (((k + 1) >> 6) == h) rowk[q][c] = nextrow;  // k=127: (128>>6)=2, skipped
        // single barrier per step: next step's publishes go to buffer q (no WAR)
    }

    float* __restrict__ out = QT + b * NMAT;
    #pragma unroll
    for (int i = 0; i < 64; ++i) {
        int r = r0 + i;
        out[r * HALF + c] = 2.0f * reg[i] - (r == c ? 1.0f : 0.0f);
    }
}

// ---------------------------------------------------------------------------
// K2: path table via tree recursion:
//   P[v] = P[(v & 2^{L-2}-1) | 2^{L-2}] * Q^T_{bit_{L-2}(v)}   (L = bitlen v)
// => P[v] = P[(v&127)|128] * prod_{d=7}^{L-2} Q^T_{bit_d(v)}  (same op order
// as reference -> fp-identical).  Launched twice:
//   base:   vbase=0,   d0=0 (direct chains, rows 0..255; factor d iff v>>(d+1)>0)
//   expand: vbase=256, d0=7 (start from P[(v&127)|128], <=4 steps)
// 8 rows/block; thread = (row rg, 4-col chunk jj); double-buffered LDS row
// vectors -> 1 barrier/step; float4 Q loads from L2.
// ---------------------------------------------------------------------------
__global__ __launch_bounds__(256) void path_steps(const float* __restrict__ QT,
                                                  const float* __restrict__ ident,
                                                  float* __restrict__ P,
                                                  int vbase, int d0) {
    __shared__ float vs[2][8][HALF];
    const int t    = threadIdx.x;
    const int rg   = t >> 5;                 // row in block (0..7)
    const int jj   = (t & 31) << 2;          // 4-col chunk
    const int v    = vbase + (blockIdx.x << 3) + rg;
    const int vmax = vbase + (blockIdx.x << 3) + 7;

    float4 sv;
    if (d0 == 0) {
        sv = *(const float4*)&ident[jj];
    } else {
        const int u = (v & 127) | 128;       // bitlen-8 ancestor (base row)
        sv = *(const float4*)&P[u * HALF + jj];
    }
    *(float4*)&vs[0][rg][jj] = sv;
    __syncthreads();

    int cur = 0;
    for (int d = d0; d < 13; ++d) {
        if ((vmax >> (d + 1)) == 0) break;           // block-uniform
        const bool valid = (v >> (d + 1)) > 0;       // row still on its path?
        const float* __restrict__ Qm = QT + (((v >> d) & 1) ? NMAT : 0);
        float4 acc = make_float4(0.f, 0.f, 0.f, 0.f);
        #pragma unroll 4
        for (int cc = 0; cc < 128; cc += 4) {
            float4 v4 = *(const float4*)&vs[cur][rg][cc];   // 2-addr bcast (free)
            float4 q0 = *(const float4*)&Qm[(cc+0)*HALF + jj];
            float4 q1 = *(const float4*)&Qm[(cc+1)*HALF + jj];
            float4 q2 = *(const float4*)&Qm[(cc+2)*HALF + jj];
            float4 q3 = *(const float4*)&Qm[(cc+3)*HALF + jj];
            acc.x = fmaf(v4.x,q0.x, fmaf(v4.y,q1.x, fmaf(v4.z,q2.x, fmaf(v4.w,q3.x, acc.x))));
            acc.y = fmaf(v4.x,q0.y, fmaf(v4.y,q1.y, fmaf(v4.z,q2.y, fmaf(v4.w,q3.y, acc.y))));
            acc.z = fmaf(v4.x,q0.z, fmaf(v4.y,q1.z, fmaf(v4.z,q2.z, fmaf(v4.w,q3.z, acc.z))));
            acc.w = fmaf(v4.x,q0.w, fmaf(v4.y,q1.w, fmaf(v4.z,q2.w, fmaf(v4.w,q3.w, acc.w))));
        }
        if (!valid) acc = *(const float4*)&vs[cur][rg][jj];  // carry forward
        *(float4*)&vs[cur ^ 1][rg][jj] = acc;   // other buffer: no WAR
        __syncthreads();
        cur ^= 1;
    }
    *(float4*)&P[v * HALF + jj] = *(const float4*)&vs[cur][rg][jj];
}

// ---------------------------------------------------------------------------
// K3: emit [B,S,256] = content ++ pos, float4: one wave per token,
// one 16B load + one 16B store per thread. Write-bound (~134 MB).
// ---------------------------------------------------------------------------
__global__ __launch_bounds__(256) void emit_out(const int* __restrict__ tt,
                                                const int* __restrict__ tv,
                                                const int* __restrict__ np,
                                                const float* __restrict__ P,
                                                const float* __restrict__ emb,
                                                float* __restrict__ out) {
    const int i  = (blockIdx.x << 2) + (threadIdx.x >> 6);
    const int jj = (threadIdx.x & 63) << 2;
    const int ty = tt[i];
    const int v  = tv[i];
    float4 val;
    if (jj < 128) {
        if (ty == 0)      val = *(const float4*)&emb[jj];
        else if (ty == 1) val = *(const float4*)&emb[(v + 1) * HALF + jj];
        else if (ty == 2) val = *(const float4*)&emb[(v + 5) * HALF + jj];
        else if (ty == 4) {
            int vc = v < 0 ? 0 : (v > 4095 ? 4095 : v);
            val = *(const float4*)&P[vc * HALF + jj];
        } else val = (v == -1) ? *(const float4*)&emb[10 * HALF + jj]
                               : make_float4(0.f, 0.f, 0.f, 0.f);
    } else {
        const int p = np[i];
        val = *(const float4*)&P[p * HALF + (jj - 128)];
    }
    *(float4*)&out[i * 256 + jj] = val;
}

extern "C" void kernel_launch(void* const* d_in, const int* in_sizes, int n_in,
                              void* d_out, int out_size, void* d_ws, size_t ws_size,
                              hipStream_t stream) {
    const int*   token_types = (const int*)  d_in[0];
    const int*   token_vals  = (const int*)  d_in[1];
    const int*   node_pos    = (const int*)  d_in[2];
    const float* prim        = (const float*)d_in[3];
    const float* ident       = (const float*)d_in[4];
    const float* emb         = (const float*)d_in[5];
    float* out = (float*)d_out;

    // workspace: QT[2][128][128] | (gap) | P[4096][128]
    float* QT = (float*)d_ws;
    float* P  = (float*)((char*)d_ws + 262144);

    cayley_qt  <<<2,   256, 0, stream>>>(prim, QT);
    path_steps <<<32,  256, 0, stream>>>(QT, ident, P, 0,   0);   // rows [0,256)
    path_steps <<<480, 256, 0, stream>>>(QT, ident, P, 256, 7);   // rows [256,4096)
    emit_out   <<<NTOK / 4, 256, 0, stream>>>(token_types, token_vals, node_pos,
                                              P, emb, out);
}

// Round 4
// 298.818 us; speedup vs baseline: 3.1333x; 2.0468x over previous
//
#include <hip/hip_runtime.h>

#define HALF 128
#define NMAT 16384   // 128*128
#define NTOK 131072  // 32*4096

// ---------------------------------------------------------------------------
// K1: fused Cayley -> QT.  Q^T = N^{-1}(2I - N) = 2 N^{-1} - I,  N = I + A/2.
// BLOCKED Gauss-Jordan (panel b=16): 8 block-steps x 2 barriers instead of
// 128 x 1 (round-3 lesson: per-step barrier+LDS latency at 1 wave/SIMD costs
// ~7K cycles regardless of per-step work; shrink the step count).
// Block-step s (K = [16s,16s+16), pre-step W):
//   D = W[K,K]; C = W[:,K]; R = W[K,:]
//   W[J,J'] -= C*(Dinv*R);  W[J,K] = -C*Dinv;  W[K,J'] = Dinv*R;  W[K,K] = Dinv
// (composition of 16 no-pivot scalar GJ steps -- same elimination order as the
// verified round-3 kernel, re-associated).  Dinv computed by wave 0 in
// registers via shuffle-GJ (no barriers).  512 threads: thread owns 32 rows of
// one column in VGPRs (constant indices only -- round-2 scratch lesson).
// ---------------------------------------------------------------------------
__global__ __launch_bounds__(512) void cayley_qt(const float* __restrict__ prim,
                                                 float* __restrict__ QT) {
    __shared__ __align__(16) float Xs[128 * 129];     // padded input stage
    __shared__ __align__(16) float CpT[2][16][132];   // panel cols, [m][r], pad->2-way max
    __shared__ __align__(16) float Rp [2][16][128];   // panel rows, [j][c]
    __shared__ __align__(16) float Dcol[2][16][20];   // Dcol[j][m] = Dinv[m][j], 16B-aligned rows

    const int b = blockIdx.x;
    const float* __restrict__ X = prim + b * NMAT;
    const int t  = threadIdx.x;
    const int c  = t & 127;          // owned column
    const int q  = t >> 7;           // row quarter (wave-uniform)
    const int r0 = q << 5;           // owns rows r0..r0+31

    for (int idx4 = t; idx4 < 4096; idx4 += 512) {
        int gi = idx4 << 2;
        float4 v = *(const float4*)(X + gi);
        int r = gi >> 7, cc = gi & 127;
        float* p = &Xs[r * 129 + cc];
        p[0] = v.x; p[1] = v.y; p[2] = v.z; p[3] = v.w;
    }
    __syncthreads();

    // reg[i] = N[r0+i][c];  A = tril(X) - tril(X)^T
    float reg[32];
    #pragma unroll
    for (int i = 0; i < 32; ++i) {
        int r  = r0 + i;
        int mx = r > c ? r : c;
        int mn = r ^ c ^ mx;
        float x = Xs[mx * 129 + mn];
        reg[i] = (r == c) ? 1.0f : (r > c ? 0.5f * x : -0.5f * x);
    }

    #pragma unroll
    for (int s = 0; s < 8; ++s) {
        const int  p     = s & 1;
        const int  k0    = s << 4;
        const int  q0    = s >> 1;          // quarter holding rows K
        const int  kl    = (s & 1) << 4;    // local row index of k0 in that quarter
        const bool panel = (c >= k0) && (c < k0 + 16);

        // ---- publish pre-step panel (into buffer p; other buffer still live)
        if (panel) {
            const int m = c - k0;
            #pragma unroll
            for (int i = 0; i < 32; i += 4)
                *(float4*)&CpT[p][m][r0 + i] =
                    make_float4(reg[i], reg[i+1], reg[i+2], reg[i+3]);
        }
        if (q == q0) {
            #pragma unroll
            for (int j = 0; j < 16; ++j) Rp[p][j][c] = reg[kl + j];
        }
        __syncthreads();

        // ---- wave 0: invert D (16x16) in registers, shuffle-based GJ
        if (t < 64) {
            const int cp = t & 15, q4 = t >> 4;   // lane owns D[q4*4..+3][cp]
            float dd[4];
            #pragma unroll
            for (int i = 0; i < 4; ++i) dd[i] = Rp[p][q4 * 4 + i][k0 + cp];
            #pragma unroll
            for (int k = 0; k < 16; ++k) {
                float cv[4];
                #pragma unroll
                for (int i = 0; i < 4; ++i) cv[i] = __shfl(dd[i], (q4 << 4) | k);
                float rv   = __shfl(dd[k & 3], ((k >> 2) << 4) | cp);  // D[k][cp]
                float dkk  = __shfl(rv, k);
                float dinv = 1.0f / dkk;
                float sv   = rv * dinv;
                bool  own  = (cp == k);
                float rf   = own ? dinv : sv;
                #pragma unroll
                for (int i = 0; i < 4; ++i)
                    dd[i] = own ? (-dd[i] * dinv) : fmaf(-cv[i], sv, dd[i]);
                dd[k & 3] = (q4 == (k >> 2)) ? rf : dd[k & 3];
            }
            #pragma unroll
            for (int i = 0; i < 4; ++i) Dcol[p][cp][q4 * 4 + i] = dd[i];
        }
        __syncthreads();

        // ---- coefficients: RB[m]=(Dinv*R)[m][c] (non-panel) or Dinv[:,c-k0]
        float coeff[16];
        if (!panel) {
            #pragma unroll
            for (int j = 0; j < 16; ++j) coeff[j] = 0.0f;
            #pragma unroll
            for (int j = 0; j < 16; ++j) {
                float rpj = Rp[p][j][c];
                #pragma unroll
                for (int mq = 0; mq < 16; mq += 4) {
                    float4 dv = *(const float4*)&Dcol[p][j][mq];
                    coeff[mq+0] = fmaf(dv.x, rpj, coeff[mq+0]);
                    coeff[mq+1] = fmaf(dv.y, rpj, coeff[mq+1]);
                    coeff[mq+2] = fmaf(dv.z, rpj, coeff[mq+2]);
                    coeff[mq+3] = fmaf(dv.w, rpj, coeff[mq+3]);
                }
            }
        } else {
            const int mp = c - k0;
            #pragma unroll
            for (int j = 0; j < 16; ++j) coeff[j] = Dcol[p][mp][j];  // Dinv[j][mp]
            #pragma unroll
            for (int i = 0; i < 32; ++i) reg[i] = 0.0f;  // col block = -C*Dinv
        }

        // ---- rank-16 update: reg[i] -= sum_m C[r0+i][m] * coeff[m]
        #pragma unroll
        for (int m = 0; m < 16; ++m) {
            float cm = coeff[m];
            #pragma unroll
            for (int i = 0; i < 32; i += 4) {
                float4 c4 = *(const float4*)&CpT[p][m][r0 + i];   // broadcast
                reg[i+0] = fmaf(-c4.x, cm, reg[i+0]);
                reg[i+1] = fmaf(-c4.y, cm, reg[i+1]);
                reg[i+2] = fmaf(-c4.z, cm, reg[i+2]);
                reg[i+3] = fmaf(-c4.w, cm, reg[i+3]);
            }
        }
        // rows K: W[K,J'] = Dinv*R (non-panel), W[K,K] = Dinv (panel)
        if (q == q0) {
            #pragma unroll
            for (int j = 0; j < 16; ++j) reg[kl + j] = coeff[j];
        }
        // next step publishes into buffer p^1; its first barrier guards reuse
    }

    float* __restrict__ out = QT + b * NMAT;
    #pragma unroll
    for (int i = 0; i < 32; ++i) {
        int r = r0 + i;
        out[r * HALF + c] = 2.0f * reg[i] - (r == c ? 1.0f : 0.0f);
    }
}

// ---------------------------------------------------------------------------
// K2: path table via tree recursion:
//   P[v] = P[(v&127)|128] * prod_{d=7}^{L-2} Q^T_{bit_d(v)}  (same op order
// as reference -> fp-identical).  base: rows [0,256) direct; expand: rest.
// ---------------------------------------------------------------------------
__global__ __launch_bounds__(256) void path_steps(const float* __restrict__ QT,
                                                  const float* __restrict__ ident,
                                                  float* __restrict__ P,
                                                  int vbase, int d0) {
    __shared__ float vs[2][8][HALF];
    const int t    = threadIdx.x;
    const int rg   = t >> 5;                 // row in block (0..7)
    const int jj   = (t & 31) << 2;          // 4-col chunk
    const int v    = vbase + (blockIdx.x << 3) + rg;
    const int vmax = vbase + (blockIdx.x << 3) + 7;

    float4 sv;
    if (d0 == 0) {
        sv = *(const float4*)&ident[jj];
    } else {
        const int u = (v & 127) | 128;       // bitlen-8 ancestor (base row)
        sv = *(const float4*)&P[u * HALF + jj];
    }
    *(float4*)&vs[0][rg][jj] = sv;
    __syncthreads();

    int cur = 0;
    for (int d = d0; d < 13; ++d) {
        if ((vmax >> (d + 1)) == 0) break;           // block-uniform
        const bool valid = (v >> (d + 1)) > 0;       // row still on its path?
        const float* __restrict__ Qm = QT + (((v >> d) & 1) ? NMAT : 0);
        float4 acc = make_float4(0.f, 0.f, 0.f, 0.f);
        #pragma unroll 4
        for (int cc = 0; cc < 128; cc += 4) {
            float4 v4 = *(const float4*)&vs[cur][rg][cc];   // 2-addr bcast (free)
            float4 q0 = *(const float4*)&Qm[(cc+0)*HALF + jj];
            float4 q1 = *(const float4*)&Qm[(cc+1)*HALF + jj];
            float4 q2 = *(const float4*)&Qm[(cc+2)*HALF + jj];
            float4 q3 = *(const float4*)&Qm[(cc+3)*HALF + jj];
            acc.x = fmaf(v4.x,q0.x, fmaf(v4.y,q1.x, fmaf(v4.z,q2.x, fmaf(v4.w,q3.x, acc.x))));
            acc.y = fmaf(v4.x,q0.y, fmaf(v4.y,q1.y, fmaf(v4.z,q2.y, fmaf(v4.w,q3.y, acc.y))));
            acc.z = fmaf(v4.x,q0.z, fmaf(v4.y,q1.z, fmaf(v4.z,q2.z, fmaf(v4.w,q3.z, acc.z))));
            acc.w = fmaf(v4.x,q0.w, fmaf(v4.y,q1.w, fmaf(v4.z,q2.w, fmaf(v4.w,q3.w, acc.w))));
        }
        if (!valid) acc = *(const float4*)&vs[cur][rg][jj];  // carry forward
        *(float4*)&vs[cur ^ 1][rg][jj] = acc;   // other buffer: no WAR
        __syncthreads();
        cur ^= 1;
    }
    *(float4*)&P[v * HALF + jj] = *(const float4*)&vs[cur][rg][jj];
}

// ---------------------------------------------------------------------------
// K3: emit [B,S,256] = content ++ pos, float4: one wave per token.
// ---------------------------------------------------------------------------
__global__ __launch_bounds__(256) void emit_out(const int* __restrict__ tt,
                                                const int* __restrict__ tv,
                                                const int* __restrict__ np,
                                                const float* __restrict__ P,
                                                const float* __restrict__ emb,
                                                float* __restrict__ out) {
    const int i  = (blockIdx.x << 2) + (threadIdx.x >> 6);
    const int jj = (threadIdx.x & 63) << 2;
    const int ty = tt[i];
    const int v  = tv[i];
    float4 val;
    if (jj < 128) {
        if (ty == 0)      val = *(const float4*)&emb[jj];
        else if (ty == 1) val = *(const float4*)&emb[(v + 1) * HALF + jj];
        else if (ty == 2) val = *(const float4*)&emb[(v + 5) * HALF + jj];
        else if (ty == 4) {
            int vc = v < 0 ? 0 : (v > 4095 ? 4095 : v);
            val = *(const float4*)&P[vc * HALF + jj];
        } else val = (v == -1) ? *(const float4*)&emb[10 * HALF + jj]
                               : make_float4(0.f, 0.f, 0.f, 0.f);
    } else {
        const int p = np[i];
        val = *(const float4*)&P[p * HALF + (jj - 128)];
    }
    *(float4*)&out[i * 256 + jj] = val;
}

extern "C" void kernel_launch(void* const* d_in, const int* in_sizes, int n_in,
                              void* d_out, int out_size, void* d_ws, size_t ws_size,
                              hipStream_t stream) {
    const int*   token_types = (const int*)  d_in[0];
    const int*   token_vals  = (const int*)  d_in[1];
    const int*   node_pos    = (const int*)  d_in[2];
    const float* prim        = (const float*)d_in[3];
    const float* ident       = (const float*)d_in[4];
    const float* emb         = (const float*)d_in[5];
    float* out = (float*)d_out;

    // workspace: QT[2][128][128] | (gap) | P[4096][128]
    float* QT = (float*)d_ws;
    float* P  = (float*)((char*)d_ws + 262144);

    cayley_qt  <<<2,   512, 0, stream>>>(prim, QT);
    path_steps <<<32,  256, 0, stream>>>(QT, ident, P, 0,   0);   // rows [0,256)
    path_steps <<<480, 256, 0, stream>>>(QT, ident, P, 256, 7);   // rows [256,4096)
    emit_out   <<<NTOK / 4, 256, 0, stream>>>(token_types, token_vals, node_pos,
                                              P, emb, out);
}